// Round 4
// baseline (293.208 us; speedup 1.0000x reference)
//
#include <hip/hip_runtime.h>
#include <hip/hip_bf16.h>

// LSS voxel pooling: B=2,N=6,D=48,FH=16,FW=44,C=80 -> out [2,80,1,256,256]
// R3 analysis: latency-bound — all pipes idle (VALUBusy 2%, HBM 12%,
// occupancy 18.5%), only 576 blocks with serial per-thread item loops.
// R4: one thread per (column, channel-quad) item; 2112 blocks; per-block
// parallel geometry (192 threads) + 240 one-item threads with 16-way MLP.
// Atomic count unchanged (2.0M) — discriminates latency-bound vs atomic-bound.
//
// Numerics (verified R1-R3, absmax 0.016): f64 geometry seeded with bit-exact
// f32 frustum values + f32-valued bounds constants; trunc-toward-zero.

#define NCH       80
#define GRID_HW   65536    // 256*256
#define OUT_PER_B 5242880  // 80*65536
#define HSTRIDE   3520     // 44*80 floats between h rows
#define COLS_PER_BN 2112   // 48*44
#define COLS_PER_BLK 12

__device__ inline void inv3(const double a[9], double inv[9]) {
    double c00 =  a[4]*a[8] - a[5]*a[7];
    double c01 = -(a[3]*a[8] - a[5]*a[6]);
    double c02 =  a[3]*a[7] - a[4]*a[6];
    double det = a[0]*c00 + a[1]*c01 + a[2]*c02;
    double id  = 1.0/det;
    inv[0] = c00*id;
    inv[1] = (a[2]*a[7]-a[1]*a[8])*id;
    inv[2] = (a[1]*a[5]-a[2]*a[4])*id;
    inv[3] = c01*id;
    inv[4] = (a[0]*a[8]-a[2]*a[6])*id;
    inv[5] = (a[2]*a[3]-a[0]*a[5])*id;
    inv[6] = c02*id;
    inv[7] = (a[1]*a[6]-a[0]*a[7])*id;
    inv[8] = (a[0]*a[4]-a[1]*a[3])*id;
}

// ws[bn*24 + 0..8]=inv(post_rots), [9..17]=rots@inv(intrins),
// [18..20]=post_trans, [21..23]=trans (double)
__global__ void prep_kernel(const float* __restrict__ rots,
                            const float* __restrict__ trans,
                            const float* __restrict__ intrins,
                            const float* __restrict__ post_rots,
                            const float* __restrict__ post_trans,
                            double* __restrict__ ws) {
    int bn = threadIdx.x;
    if (bn >= 12) return;
    double pr[9], kk[9], rt[9], ipr[9], ik[9];
    #pragma unroll
    for (int i = 0; i < 9; i++) {
        pr[i] = (double)post_rots[bn*9 + i];
        kk[i] = (double)intrins[bn*9 + i];
        rt[i] = (double)rots[bn*9 + i];
    }
    inv3(pr, ipr);
    inv3(kk, ik);
    double* o = ws + bn*24;
    #pragma unroll
    for (int i = 0; i < 9; i++) o[i] = ipr[i];
    #pragma unroll
    for (int r = 0; r < 3; r++)
        #pragma unroll
        for (int c = 0; c < 3; c++)
            o[9 + r*3 + c] = rt[r*3+0]*ik[0*3+c] + rt[r*3+1]*ik[1*3+c] + rt[r*3+2]*ik[2*3+c];
    #pragma unroll
    for (int i = 0; i < 3; i++) o[18 + i] = (double)post_trans[bn*3 + i];
    #pragma unroll
    for (int i = 0; i < 3; i++) o[21 + i] = (double)trans[bn*3 + i];
}

__global__ __launch_bounds__(256) void zero_kernel(float4* __restrict__ out, int n4) {
    int i = blockIdx.x * 256 + threadIdx.x;
    int stride = gridDim.x * 256;
    for (; i < n4; i += stride) out[i] = make_float4(0.f, 0.f, 0.f, 0.f);
}

// Block = 12 columns of one (bn,d). Grid = 25344/12 = 2112 blocks.
// (2112 cols per bn, 176 blocks per bn -> blocks never straddle bn.)
__global__ __launch_bounds__(256) void scatter_kernel(const float* __restrict__ x,
                                                      const double* __restrict__ ws,
                                                      float* __restrict__ out) {
    __shared__ int      s_base[COLS_PER_BLK * 16];  // per (lcol,h) voxel base or -1
    __shared__ int      s_colbase[COLS_PER_BLK];
    __shared__ unsigned s_mask[COLS_PER_BLK];       // h-bits matching colbase
    __shared__ unsigned s_fb[COLS_PER_BLK];         // h-bits with differing base (fallback)

    const int tid  = threadIdx.x;
    const int bid  = blockIdx.x;
    const int bn   = bid / 176;
    const int col0 = bid * COLS_PER_BLK;
    const int b    = bn / 6;
    const double* t = ws + bn * 24;

    // ---- phase 1: parallel per-(h,col) geometry ----
    if (tid < COLS_PER_BLK * 16) {
        const int lcol = tid >> 4;
        const int h    = tid & 15;
        const int rem  = col0 + lcol - bn * COLS_PER_BN;
        const int d    = rem / 44;
        const int w    = rem - d * 44;

        float xsv = (w == 43) ? 703.0f : (float)((double)w * (703.0 / 43.0));
        float ysv = (float)(h * 17);
        float dsv = __fadd_rn(2.0f, __fmul_rn((float)(56.0 / 48.0), (float)d));

        double px = (double)xsv - t[18];
        double py = (double)ysv - t[19];
        double pz = (double)dsv - t[20];
        double q0 = t[0]*px + t[1]*py + t[2]*pz;
        double q1 = t[3]*px + t[4]*py + t[5]*pz;
        double q2 = t[6]*px + t[7]*py + t[8]*pz;
        q0 *= q2;
        q1 *= q2;
        double e0 = t[9]*q0  + t[10]*q1 + t[11]*q2 + t[21];
        double e1 = t[12]*q0 + t[13]*q1 + t[14]*q2 + t[22];
        double e2 = t[15]*q0 + t[16]*q1 + t[17]*q2 + t[23];

        const double lxy = (double)(-51.2f);
        const double dxy = (double)(0.4f);
        int gx = (int)((e0 - lxy) / dxy);
        int gy = (int)((e1 - lxy) / dxy);
        int gz = (int)((e2 - (double)(-10.0f)) / (double)(20.0f));
        int base = -1;
        if (gx >= 0 && gx < 256 && gy >= 0 && gy < 256 && gz == 0)
            base = b * OUT_PER_B + gy * 256 + gx;
        s_base[lcol * 16 + h] = base;
    }
    __syncthreads();

    // ---- phase 1b: per-column base + masks (12 threads) ----
    if (tid < COLS_PER_BLK) {
        int cb = -1; unsigned mm = 0, fb = 0;
        #pragma unroll
        for (int h = 0; h < 16; h++) {
            int pb = s_base[tid * 16 + h];
            if (pb >= 0) {
                if (cb < 0) cb = pb;
                if (pb == cb) mm |= (1u << h);
                else          fb |= (1u << h);
            }
        }
        s_colbase[tid] = cb;
        s_mask[tid]    = mm;
        s_fb[tid]      = fb;
    }
    __syncthreads();

    // ---- phase 2: one item per thread: (lcol, c4) ----
    if (tid < COLS_PER_BLK * 20) {
        const int lcol = tid / 20;
        const int c4   = tid - lcol * 20;
        unsigned mm = s_mask[lcol];
        unsigned fb = s_fb[lcol];
        if (mm | fb) {
            const int rem = col0 + lcol - bn * COLS_PER_BN;
            const int d   = rem / 44;
            const int w   = rem - d * 44;
            const float* xb = x + ((size_t)(bn * 48 + d) * 704 + w) * NCH + c4 * 4;
            float ax = 0.f, ay = 0.f, az = 0.f, aw = 0.f;
            #pragma unroll
            for (int h = 0; h < 16; h++) {
                if ((mm >> h) & 1u) {
                    float4 v = *(const float4*)(xb + h * HSTRIDE);
                    ax += v.x; ay += v.y; az += v.z; aw += v.w;
                } else if ((fb >> h) & 1u) {   // general-input path (unused here)
                    float4 v = *(const float4*)(xb + h * HSTRIDE);
                    int pb = s_base[lcol * 16 + h];
                    atomicAdd(out + pb + (size_t)(c4*4 + 0) * GRID_HW, v.x);
                    atomicAdd(out + pb + (size_t)(c4*4 + 1) * GRID_HW, v.y);
                    atomicAdd(out + pb + (size_t)(c4*4 + 2) * GRID_HW, v.z);
                    atomicAdd(out + pb + (size_t)(c4*4 + 3) * GRID_HW, v.w);
                }
            }
            if (mm) {
                int cb = s_colbase[lcol];
                atomicAdd(out + cb + (size_t)(c4*4 + 0) * GRID_HW, ax);
                atomicAdd(out + cb + (size_t)(c4*4 + 1) * GRID_HW, ay);
                atomicAdd(out + cb + (size_t)(c4*4 + 2) * GRID_HW, az);
                atomicAdd(out + cb + (size_t)(c4*4 + 3) * GRID_HW, aw);
            }
        }
    }
}

extern "C" void kernel_launch(void* const* d_in, const int* in_sizes, int n_in,
                              void* d_out, int out_size, void* d_ws, size_t ws_size,
                              hipStream_t stream) {
    const float* x          = (const float*)d_in[0];
    const float* rots       = (const float*)d_in[1];
    const float* trans      = (const float*)d_in[2];
    const float* intrins    = (const float*)d_in[3];
    const float* post_rots  = (const float*)d_in[4];
    const float* post_trans = (const float*)d_in[5];
    float*  out = (float*)d_out;
    double* ws  = (double*)d_ws;

    zero_kernel<<<2560, 256, 0, stream>>>((float4*)out, out_size / 4);
    prep_kernel<<<1, 64, 0, stream>>>(rots, trans, intrins, post_rots, post_trans, ws);
    scatter_kernel<<<2112, 256, 0, stream>>>(x, ws, out);
}

// Round 5
// 238.064 us; speedup vs baseline: 1.2316x; 1.2316x over previous
//
#include <hip/hip_runtime.h>
#include <hip/hip_bf16.h>

// LSS voxel pooling: B=2,N=6,D=48,FH=16,FW=44,C=80 -> out [2,80,1,256,256]
// R4 post-mortem: occupancy 18->55% with dur flat => NOT latency-bound.
// Bound = uncoalesced atomic transactions: out is channel-major, so a
// column-flush's 80 atomics are 256KB apart -> 64 L2 transactions per wave
// instr; ~2M transactions at ~23G/s ~= 90us floor.
// R5: flush into voxel-major scratch S[b][vox][80] (320B contiguous per
// column => coalesced atomics, ~8x fewer transactions), then dense
// transpose S -> out (fully coalesced, also replaces out-zeroing).
//
// Numerics (verified R1-R4, absmax 0.016): f64 geometry seeded with bit-exact
// f32 frustum values + f32-valued bounds constants; trunc-toward-zero.

#define NCH       80
#define GRID_HW   65536    // 256*256
#define OUT_PER_B 5242880  // 80*65536
#define HSTRIDE   3520     // 44*80 floats between h rows
#define PTS_PER_BN 33792   // 48*16*44
#define S_FLOATS  10485760 // 2*65536*80
#define S_BYTES   41943040

__device__ inline void inv3(const double a[9], double inv[9]) {
    double c00 =  a[4]*a[8] - a[5]*a[7];
    double c01 = -(a[3]*a[8] - a[5]*a[6]);
    double c02 =  a[3]*a[7] - a[4]*a[6];
    double det = a[0]*c00 + a[1]*c01 + a[2]*c02;
    double id  = 1.0/det;
    inv[0] = c00*id;
    inv[1] = (a[2]*a[7]-a[1]*a[8])*id;
    inv[2] = (a[1]*a[5]-a[2]*a[4])*id;
    inv[3] = c01*id;
    inv[4] = (a[0]*a[8]-a[2]*a[6])*id;
    inv[5] = (a[2]*a[3]-a[0]*a[5])*id;
    inv[6] = c02*id;
    inv[7] = (a[1]*a[6]-a[0]*a[7])*id;
    inv[8] = (a[0]*a[4]-a[1]*a[3])*id;
}

// tw[bn*24 + 0..8]=inv(post_rots), [9..17]=rots@inv(intrins),
// [18..20]=post_trans, [21..23]=trans (double)
__global__ void prep_kernel(const float* __restrict__ rots,
                            const float* __restrict__ trans,
                            const float* __restrict__ intrins,
                            const float* __restrict__ post_rots,
                            const float* __restrict__ post_trans,
                            double* __restrict__ tw) {
    int bn = threadIdx.x;
    if (bn >= 12) return;
    double pr[9], kk[9], rt[9], ipr[9], ik[9];
    #pragma unroll
    for (int i = 0; i < 9; i++) {
        pr[i] = (double)post_rots[bn*9 + i];
        kk[i] = (double)intrins[bn*9 + i];
        rt[i] = (double)rots[bn*9 + i];
    }
    inv3(pr, ipr);
    inv3(kk, ik);
    double* o = tw + bn*24;
    #pragma unroll
    for (int i = 0; i < 9; i++) o[i] = ipr[i];
    #pragma unroll
    for (int r = 0; r < 3; r++)
        #pragma unroll
        for (int c = 0; c < 3; c++)
            o[9 + r*3 + c] = rt[r*3+0]*ik[0*3+c] + rt[r*3+1]*ik[1*3+c] + rt[r*3+2]*ik[2*3+c];
    #pragma unroll
    for (int i = 0; i < 3; i++) o[18 + i] = (double)post_trans[bn*3 + i];
    #pragma unroll
    for (int i = 0; i < 3; i++) o[21 + i] = (double)trans[bn*3 + i];
}

__global__ __launch_bounds__(256) void zero_kernel(float4* __restrict__ p, int n4) {
    int i = blockIdx.x * 256 + threadIdx.x;
    int stride = gridDim.x * 256;
    for (; i < n4; i += stride) p[i] = make_float4(0.f, 0.f, 0.f, 0.f);
}

// ---- shared geometry: fills s_base (vox id = b*65536+gy*256+gx, or -1),
//      column base/masks. Block = one (bn,d) slice. ----
__device__ inline void geom_phase(const double* __restrict__ ws,
                                  int bn, int d, int tid,
                                  int* s_base, int* s_colbase,
                                  unsigned* s_mask, unsigned* s_fb) {
    const int b = bn / 6;
    const double* t = ws + bn * 24;
    const float dsv = __fadd_rn(2.0f, __fmul_rn((float)(56.0 / 48.0), (float)d));

    for (int idx = tid; idx < 704; idx += 256) {
        const int h = idx / 44;
        const int w = idx - h * 44;
        float xsv = (w == 43) ? 703.0f : (float)((double)w * (703.0 / 43.0));
        float ysv = (float)(h * 17);

        double px = (double)xsv - t[18];
        double py = (double)ysv - t[19];
        double pz = (double)dsv - t[20];
        double q0 = t[0]*px + t[1]*py + t[2]*pz;
        double q1 = t[3]*px + t[4]*py + t[5]*pz;
        double q2 = t[6]*px + t[7]*py + t[8]*pz;
        q0 *= q2;
        q1 *= q2;
        double e0 = t[9]*q0  + t[10]*q1 + t[11]*q2 + t[21];
        double e1 = t[12]*q0 + t[13]*q1 + t[14]*q2 + t[22];
        double e2 = t[15]*q0 + t[16]*q1 + t[17]*q2 + t[23];

        const double lxy = (double)(-51.2f);
        const double dxy = (double)(0.4f);
        int gx = (int)((e0 - lxy) / dxy);
        int gy = (int)((e1 - lxy) / dxy);
        int gz = (int)((e2 - (double)(-10.0f)) / (double)(20.0f));
        int base = -1;
        if (gx >= 0 && gx < 256 && gy >= 0 && gy < 256 && gz == 0)
            base = (b << 16) | (gy << 8) | gx;     // voxel id
        s_base[idx] = base;
    }
    __syncthreads();

    if (tid < 44) {
        int cb = -1; unsigned mm = 0, fb = 0;
        #pragma unroll
        for (int h = 0; h < 16; h++) {
            int pb = s_base[h * 44 + tid];
            if (pb >= 0) {
                if (cb < 0) cb = pb;
                if (pb == cb) mm |= (1u << h);
                else          fb |= (1u << h);
            }
        }
        s_colbase[tid] = cb;
        s_mask[tid]    = mm;
        s_fb[tid]      = fb;
    }
    __syncthreads();
}

// Main path: flush into voxel-major S[vox][80] with coalesced atomics.
__global__ __launch_bounds__(256) void scatter_grid_kernel(const float* __restrict__ x,
                                                           const double* __restrict__ ws,
                                                           float* __restrict__ S) {
    __shared__ int      s_base[704];
    __shared__ int      s_colbase[44];
    __shared__ unsigned s_mask[44];
    __shared__ unsigned s_fb[44];

    const int tid = threadIdx.x;
    const int bn  = blockIdx.x / 48;
    const int d   = blockIdx.x - bn * 48;
    geom_phase(ws, bn, d, tid, s_base, s_colbase, s_mask, s_fb);

    const float* xb0 = x + ((size_t)bn * PTS_PER_BN + (size_t)d * 704) * NCH;
    #pragma unroll
    for (int pass = 0; pass < 4; pass++) {
        int item = pass * 256 + tid;
        if (item >= 880) break;
        int w  = item / 20;
        int c4 = item - w * 20;
        unsigned mm = s_mask[w];
        unsigned fb = s_fb[w];
        if (!(mm | fb)) continue;
        const float* xb = xb0 + (size_t)w * NCH + c4 * 4;
        float ax = 0.f, ay = 0.f, az = 0.f, aw = 0.f;
        #pragma unroll
        for (int h = 0; h < 16; h++) {
            if ((mm >> h) & 1u) {
                float4 v = *(const float4*)(xb + h * HSTRIDE);
                ax += v.x; ay += v.y; az += v.z; aw += v.w;
            } else if ((fb >> h) & 1u) {   // general-input path (unused here)
                float4 v = *(const float4*)(xb + h * HSTRIDE);
                float* sp = S + (size_t)s_base[h * 44 + w] * NCH + c4 * 4;
                atomicAdd(sp + 0, v.x);
                atomicAdd(sp + 1, v.y);
                atomicAdd(sp + 2, v.z);
                atomicAdd(sp + 3, v.w);
            }
        }
        if (mm) {
            // consecutive lanes = consecutive c4 -> 320B-contiguous per column
            float* sp = S + (size_t)s_colbase[w] * NCH + c4 * 4;
            atomicAdd(sp + 0, ax);
            atomicAdd(sp + 1, ay);
            atomicAdd(sp + 2, az);
            atomicAdd(sp + 3, aw);
        }
    }
}

// S[b*65536+v][c] -> out[b][c][v]; fully coalesced both sides; writes ALL of out.
__global__ __launch_bounds__(256) void transpose_kernel(const float* __restrict__ S,
                                                        float* __restrict__ out) {
    __shared__ float tile[64 * 81];
    const int tid = threadIdx.x;
    const int b   = blockIdx.x >> 10;
    const int v0  = (blockIdx.x & 1023) * 64;
    const float* src = S + ((size_t)(b << 16) + v0) * NCH;
    #pragma unroll
    for (int i = 0; i < 20; i++) {
        int j = i * 256 + tid;          // 0..5119, coalesced read
        int v = j / 80;
        int c = j - v * 80;
        tile[v * 81 + c] = src[j];
    }
    __syncthreads();
    float* dst = out + (size_t)b * OUT_PER_B + v0;
    #pragma unroll
    for (int i = 0; i < 20; i++) {
        int k  = i * 256 + tid;
        int c  = k >> 6;                // 0..79
        int lv = k & 63;
        dst[(size_t)c * GRID_HW + lv] = tile[lv * 81 + c];  // 256B/wave-row
    }
}

// Fallback (ws too small): direct atomics into out (R3 structure).
__global__ __launch_bounds__(256) void scatter_direct_kernel(const float* __restrict__ x,
                                                             const double* __restrict__ ws,
                                                             float* __restrict__ out) {
    __shared__ int      s_base[704];
    __shared__ int      s_colbase[44];
    __shared__ unsigned s_mask[44];
    __shared__ unsigned s_fb[44];

    const int tid = threadIdx.x;
    const int bn  = blockIdx.x / 48;
    const int d   = blockIdx.x - bn * 48;
    geom_phase(ws, bn, d, tid, s_base, s_colbase, s_mask, s_fb);

    const float* xb0 = x + ((size_t)bn * PTS_PER_BN + (size_t)d * 704) * NCH;
    #pragma unroll
    for (int pass = 0; pass < 4; pass++) {
        int item = pass * 256 + tid;
        if (item >= 880) break;
        int w  = item / 20;
        int c4 = item - w * 20;
        unsigned mm = s_mask[w];
        unsigned fb = s_fb[w];
        if (!(mm | fb)) continue;
        const float* xb = xb0 + (size_t)w * NCH + c4 * 4;
        float ax = 0.f, ay = 0.f, az = 0.f, aw = 0.f;
        #pragma unroll
        for (int h = 0; h < 16; h++) {
            if ((mm >> h) & 1u) {
                float4 v = *(const float4*)(xb + h * HSTRIDE);
                ax += v.x; ay += v.y; az += v.z; aw += v.w;
            } else if ((fb >> h) & 1u) {
                float4 v = *(const float4*)(xb + h * HSTRIDE);
                int vb = s_base[h * 44 + w];
                float* o = out + (size_t)(vb >> 16) * OUT_PER_B + (vb & 65535);
                atomicAdd(o + (size_t)(c4*4 + 0) * GRID_HW, v.x);
                atomicAdd(o + (size_t)(c4*4 + 1) * GRID_HW, v.y);
                atomicAdd(o + (size_t)(c4*4 + 2) * GRID_HW, v.z);
                atomicAdd(o + (size_t)(c4*4 + 3) * GRID_HW, v.w);
            }
        }
        if (mm) {
            int vb = s_colbase[w];
            float* o = out + (size_t)(vb >> 16) * OUT_PER_B + (vb & 65535);
            atomicAdd(o + (size_t)(c4*4 + 0) * GRID_HW, ax);
            atomicAdd(o + (size_t)(c4*4 + 1) * GRID_HW, ay);
            atomicAdd(o + (size_t)(c4*4 + 2) * GRID_HW, az);
            atomicAdd(o + (size_t)(c4*4 + 3) * GRID_HW, aw);
        }
    }
}

extern "C" void kernel_launch(void* const* d_in, const int* in_sizes, int n_in,
                              void* d_out, int out_size, void* d_ws, size_t ws_size,
                              hipStream_t stream) {
    const float* x          = (const float*)d_in[0];
    const float* rots       = (const float*)d_in[1];
    const float* trans      = (const float*)d_in[2];
    const float* intrins    = (const float*)d_in[3];
    const float* post_rots  = (const float*)d_in[4];
    const float* post_trans = (const float*)d_in[5];
    float* out = (float*)d_out;

    if (ws_size >= (size_t)S_BYTES + 4096) {
        float*  S  = (float*)d_ws;
        double* tw = (double*)((char*)d_ws + S_BYTES);
        zero_kernel<<<2560, 256, 0, stream>>>((float4*)S, S_FLOATS / 4);
        prep_kernel<<<1, 64, 0, stream>>>(rots, trans, intrins, post_rots, post_trans, tw);
        scatter_grid_kernel<<<576, 256, 0, stream>>>(x, tw, S);
        transpose_kernel<<<2048, 256, 0, stream>>>(S, out);
    } else {
        double* tw = (double*)d_ws;
        zero_kernel<<<2560, 256, 0, stream>>>((float4*)out, out_size / 4);
        prep_kernel<<<1, 64, 0, stream>>>(rots, trans, intrins, post_rots, post_trans, tw);
        scatter_direct_kernel<<<576, 256, 0, stream>>>(x, tw, out);
    }
}